// Round 28
// baseline (127.450 us; speedup 1.0000x reference)
//
#include <hip/hip_runtime.h>

typedef __bf16 bf16;
typedef __bf16 bf16x8 __attribute__((ext_vector_type(8)));
typedef __bf16 bf16x4 __attribute__((ext_vector_type(4)));
typedef float f32x4 __attribute__((ext_vector_type(4)));

constexpr int D = 2048, H = 16, DPH = 128, DR = 64, DC_KV = 16, DC_Q = 512;
constexpr int QHD = 192, MEG = 256, B = 2, S = 2048;
constexpr int T = B * S;
constexpr int NDNP = 640;   // fused down-proj width (512 q + 80 kv), padded to x128
constexpr int NQX = 1280;   // q gemm width: 256 absorbed qc + 1024 rope
constexpr float EPS = 1e-7f;
constexpr float KSC = 0.104124247f;  // (1/sqrt(192)) * log2(e), folded into Qp

static __device__ __forceinline__ bf16x8 zero8() {
  bf16x8 v;
#pragma unroll
  for (int j = 0; j < 8; j++) v[j] = (bf16)0.f;
  return v;
}

static __device__ __forceinline__ void gload_lds16(const bf16* g, bf16* l) {
  __builtin_amdgcn_global_load_lds(
      (const __attribute__((address_space(1))) unsigned int*)g,
      (__attribute__((address_space(3))) unsigned int*)l, 16, 0, 0);
}

#define LGWAIT0 do { asm volatile("s_waitcnt lgkmcnt(0)" ::: "memory"); __builtin_amdgcn_sched_barrier(0); } while (0)
#define VMWAIT0 do { asm volatile("s_waitcnt vmcnt(0)" ::: "memory"); __builtin_amdgcn_sched_barrier(0); } while (0)

// ================= mega prologue: all input-independent prep in ONE launch =================
// All write regions are pairwise DISJOINT (no inter-block ordering needed):
// blocks [0,32)        : prep_w3 -> WqxT rows [0,256)    (256 thr, v-loop unroll 8)
// blocks [32,160)      : prep_w2 -> W2T                  (256 thr, v-loop unroll 8)
// blocks [160,288)     : prep_wrope -> WqxT rows [256,1280)
// blocks [288,1312)    : transpose Wq_down -> WdT rows [0,512)
// blocks [1312,1504)   : transpose Wkv_down -> WdT rows [512,592)
// blocks [1504,1552)   : zero WdT pad rows [592,640)
// blocks [1552,1808)   : rope table (f32, matches f32 jnp reference)
// blocks [1808,2832)   : cast inputs f32 -> in_bf (8 float4/thread, batched loads)
__global__ __launch_bounds__(256) void prologue_kernel(
    const float* __restrict__ inputs, const float* __restrict__ Wq_down,
    const float* __restrict__ Wq_up, const float* __restrict__ Wkv_down,
    const float* __restrict__ Wkv_up, const float* __restrict__ Wout,
    bf16* __restrict__ in_bf, bf16* __restrict__ WdT, bf16* __restrict__ WqxT,
    bf16* __restrict__ W2T, float* __restrict__ cos_t, float* __restrict__ sin_t) {
  __shared__ float smem[64 * 65];
  int bid = blockIdx.x;
  int tid = threadIdx.x;

  if (bid < 32) {                         // ---- prep_w3 (all 256 threads) ----
    int h = bid >> 1, k0 = (bid & 1) * 256;
    float (*wk)[16] = (float(*)[16])smem;
#pragma unroll
    for (int e = tid; e < 2048; e += 256) {
      int v = e >> 4, c = e & 15;
      wk[v][c] = Wkv_up[(size_t)c * (H * MEG) + h * MEG + v];
    }
    __syncthreads();
    int k = k0 + tid;
    float acc[16] = {};
#pragma unroll 8
    for (int v = 0; v < 128; v++) {
      float wq = Wq_up[(size_t)k * (H * QHD) + h * QHD + v];
#pragma unroll
      for (int c = 0; c < 16; c++) acc[c] += wk[v][c] * wq;
    }
#pragma unroll
    for (int c = 0; c < 16; c++)
      WqxT[(size_t)(h * 16 + c) * DC_Q + k] = (bf16)acc[c];
  } else if (bid < 160) {                 // ---- prep_w2 (all 256 threads) ----
    int lb = bid - 32;
    int h = lb >> 3, d0 = (lb & 7) * 256;
    float (*wv)[16] = (float(*)[16])smem;
#pragma unroll
    for (int e = tid; e < 2048; e += 256) {
      int v = e >> 4, c = e & 15;
      wv[v][c] = Wkv_up[(size_t)c * (H * MEG) + h * MEG + 128 + v];
    }
    __syncthreads();
    int d = d0 + tid;
    float acc[16] = {};
#pragma unroll 8
    for (int v = 0; v < 128; v++) {
      float wo = Wout[(size_t)(h * 128 + v) * D + d];
#pragma unroll
      for (int c = 0; c < 16; c++) acc[c] += wv[v][c] * wo;
    }
    bf16x8 o0, o1;
#pragma unroll
    for (int c = 0; c < 8; c++) { o0[c] = (bf16)acc[c]; o1[c] = (bf16)acc[8 + c]; }
    *reinterpret_cast<bf16x8*>(&W2T[(size_t)d * 256 + h * 16]) = o0;
    *reinterpret_cast<bf16x8*>(&W2T[(size_t)d * 256 + h * 16 + 8]) = o1;
  } else if (bid < 288) {                 // ---- prep_wrope ----
    int lb = bid - 160;
    int h = lb >> 3, k0 = (lb & 7) * 64;
    float (*tile)[65] = (float(*)[65])smem;
#pragma unroll
    for (int p = 0; p < 16; p++) {
      int kk = p * 4 + (tid >> 6), j = tid & 63;
      tile[kk][j] = Wq_up[(size_t)(k0 + kk) * (H * QHD) + h * QHD + 128 + j];
    }
    __syncthreads();
#pragma unroll
    for (int p = 0; p < 16; p++) {
      int n = p * 4 + (tid >> 6), k = tid & 63;
      WqxT[(size_t)(256 + h * 64 + n) * DC_Q + k0 + k] = (bf16)tile[k][n];
    }
  } else if (bid < 1504) {                // ---- transposes ----
    const float* src; bf16* dst; int K, N, k0, n0;
    if (bid < 1312) {
      int lb = bid - 288;
      src = Wq_down; dst = WdT; K = D; N = DC_Q;
      k0 = (lb >> 4) * 32; n0 = (lb & 15) * 32;
    } else {
      int lb = bid - 1312;
      src = Wkv_down; dst = WdT + (size_t)DC_Q * D; K = D; N = 80;
      k0 = (lb / 3) * 32; n0 = (lb % 3) * 32;
    }
    float (*tile)[33] = (float(*)[33])smem;
#pragma unroll
    for (int e = tid; e < 1024; e += 256) {
      int i = e >> 5, j = e & 31;
      int k = k0 + i, n = n0 + j;
      tile[i][j] = (k < K && n < N) ? src[(size_t)k * N + n] : 0.f;
    }
    __syncthreads();
#pragma unroll
    for (int e = tid; e < 1024; e += 256) {
      int jj = e >> 5, ii = e & 31;
      int n = n0 + jj, k = k0 + ii;
      if (k < K && n < N) dst[(size_t)n * D + k] = (bf16)tile[ii][jj];
    }
  } else if (bid < 1552) {                // ---- zero WdT pad rows only ----
    size_t i = (size_t)592 * D + ((size_t)(bid - 1504) * 256 + tid) * 8;
    *reinterpret_cast<bf16x8*>(WdT + i) = zero8();
  } else if (bid < 1808) {                // ---- rope table (f32) ----
    int i = (bid - 1552) * 256 + tid;     // over S*32
    int pos = i >> 5, j = i & 31;
    float invf = 1.0f / powf(10000.0f, (float)(2 * j) / 64.0f);
    float a = (float)pos * invf;
    cos_t[i] = cosf(a);
    sin_t[i] = sinf(a);
  } else {                                // ---- cast (8 rounds, batched loads) ----
    int gid = (bid - 1808) * 256 + tid;   // float4 index, 262144 per round
    float4 v[8];
#pragma unroll
    for (int k = 0; k < 8; k++)
      v[k] = *reinterpret_cast<const float4*>(inputs + ((size_t)(gid + k * 262144)) * 4);
#pragma unroll
    for (int k = 0; k < 8; k++) {
      bf16x4 o;
      o[0] = (bf16)v[k].x; o[1] = (bf16)v[k].y; o[2] = (bf16)v[k].z; o[3] = (bf16)v[k].w;
      *reinterpret_cast<bf16x4*>(in_bf + ((size_t)(gid + k * 262144)) * 4) = o;
    }
  }
}

// ======== merged rmsnorm(q) + kv prep: 1 wave per token; cqkv is bf16 ========
__global__ __launch_bounds__(256) void norm_kv_kernel(
    const bf16* __restrict__ cqkv, const float* __restrict__ qw,
    const float* __restrict__ kvw, const int* __restrict__ pos_ids,
    const float* __restrict__ cos_t, const float* __restrict__ sin_t,
    bf16* __restrict__ cqn, bf16* __restrict__ KcG, bf16* __restrict__ cTG) {
  int w = threadIdx.x >> 6, lane = threadIdx.x & 63;
  int t = blockIdx.x * 4 + w;
  int b = t >> 11, s = t & (S - 1);
  const bf16* x = cqkv + (size_t)t * NDNP;
  // ---- q rmsnorm over [0,512) ----
  bf16x8 xv = *reinterpret_cast<const bf16x8*>(x + lane * 8);
  float vv[8];
  float ss = 0.f;
#pragma unroll
  for (int j = 0; j < 8; j++) { vv[j] = (float)xv[j]; ss += vv[j] * vv[j]; }
#pragma unroll
  for (int off = 32; off; off >>= 1) ss += __shfl_xor(ss, off);
  float r = rsqrtf(ss / (float)DC_Q + EPS);
  const float* wp = qw + lane * 8;
  bf16x8 o;
#pragma unroll
  for (int j = 0; j < 8; j++) o[j] = (bf16)(vv[j] * r * wp[j]);
  *reinterpret_cast<bf16x8*>(cqn + (size_t)t * DC_Q + lane * 8) = o;
  // ---- kv prep over [512,592) ----
  const bf16* xk = x + DC_Q;
  float vk = (lane < 16) ? (float)xk[lane] : 0.f;
  float sk = vk * vk;
#pragma unroll
  for (int off = 1; off < 16; off <<= 1) sk += __shfl_xor(sk, off);
  float rk = rsqrtf(sk / 16.f + EPS);
  bf16* krow = KcG + ((size_t)t << 7);
  if (lane < 16) {
    bf16 cn = (bf16)(vk * rk * kvw[lane]);
    krow[64 + lane] = cn;
    cTG[(size_t)(b * 16 + lane) * S + s] = cn;
  } else {
    krow[64 + lane] = (bf16)0.f;   // dims 80..127 zero
  }
  if (lane < 32) {
    int j = lane;
    int pos = pos_ids[t];
    float cf = cos_t[pos * 32 + j], sf = sin_t[pos * 32 + j];
    float x0 = (float)xk[16 + 2 * j], x1 = (float)xk[16 + 2 * j + 1];
    krow[j]      = (bf16)(x0 * cf - x1 * sf);
    krow[32 + j] = (bf16)(x1 * cf + x0 * sf);
  }
}

// ---------------- bf16 MFMA GEMM, 64x128 tile, dbuf + counted vmcnt ----------------
template <typename OutT, int EPI>
__global__ __launch_bounds__(256) void gemm_bt_kernel(
    const bf16* __restrict__ A, const bf16* __restrict__ Bt,
    OutT* __restrict__ C, int M, int N, int K,
    const int* __restrict__ pos_ids = nullptr,
    const float* __restrict__ cos_t = nullptr,
    const float* __restrict__ sin_t = nullptr,
    bf16* __restrict__ Qp = nullptr) {
  __shared__ bf16 As[2][64 * 64];
  __shared__ bf16 Bs[2][128 * 64];
  int tid = threadIdx.x;
  int wid = tid >> 6, lane = tid & 63;
  int g = lane >> 4, c = lane & 15;
  int nbx = gridDim.x;                 // N / 128
  int lin = blockIdx.y * nbx + blockIdx.x;
  int cpx = (nbx * gridDim.y) >> 3;    // grid % 8 == 0 for all uses
  int swz = (lin & 7) * cpx + (lin >> 3);
  int m0 = (swz / nbx) * 64, n0 = (swz % nbx) * 128;
  int lrow8 = tid >> 3, lslot = tid & 7;

  auto stage = [&](int kt, int buf) {
    int k0 = kt << 6;
#pragma unroll
    for (int r = 0; r < 2; r++) {
      int row = r * 32 + lrow8;
      int sslot = lslot ^ (row & 7);
      gload_lds16(A + (size_t)(m0 + row) * K + k0 + sslot * 8, &As[buf][row * 64 + lslot * 8]);
    }
#pragma unroll
    for (int r = 0; r < 4; r++) {
      int row = r * 32 + lrow8;
      int sslot = lslot ^ (row & 7);
      gload_lds16(Bt + (size_t)(n0 + row) * K + k0 + sslot * 8, &Bs[buf][row * 64 + lslot * 8]);
    }
  };

  f32x4 acc[4][2] = {};
  int nk = K >> 6;
  stage(0, 0);
  __builtin_amdgcn_sched_barrier(0);
  for (int kt = 0; kt < nk; kt++) {
    int cur = kt & 1;
    __builtin_amdgcn_s_barrier();
    __builtin_amdgcn_sched_barrier(0);
    if (kt + 1 < nk) {
      stage(kt + 1, cur ^ 1);
      asm volatile("s_waitcnt vmcnt(6)" ::: "memory");
    } else {
      asm volatile("s_waitcnt vmcnt(0)" ::: "memory");
    }
    __builtin_amdgcn_sched_barrier(0);
    __builtin_amdgcn_s_barrier();
    __builtin_amdgcn_sched_barrier(0);
#pragma unroll
    for (int kk = 0; kk < 2; kk++) {
      bf16x8 af[4], bfr[2];
#pragma unroll
      for (int mi = 0; mi < 4; mi++) {
        int row = mi * 16 + c;
        int sl = (kk * 4 + g) ^ (row & 7);
        af[mi] = *reinterpret_cast<const bf16x8*>(&As[cur][row * 64 + sl * 8]);
      }
#pragma unroll
      for (int ni = 0; ni < 2; ni++) {
        int row = wid * 32 + ni * 16 + c;
        int sl = (kk * 4 + g) ^ (row & 7);
        bfr[ni] = *reinterpret_cast<const bf16x8*>(&Bs[cur][row * 64 + sl * 8]);
      }
#pragma unroll
      for (int mi = 0; mi < 4; mi++)
#pragma unroll
        for (int ni = 0; ni < 2; ni++)
          acc[mi][ni] = __builtin_amdgcn_mfma_f32_16x16x32_bf16(af[mi], bfr[ni], acc[mi][ni], 0, 0, 0);
    }
  }

  if constexpr (EPI == 0) {
#pragma unroll
    for (int mi = 0; mi < 4; mi++)
#pragma unroll
      for (int ni = 0; ni < 2; ni++)
#pragma unroll
        for (int r = 0; r < 4; r++) {
          int row = m0 + mi * 16 + g * 4 + r;
          int col = n0 + wid * 32 + ni * 16 + c;
          C[(size_t)row * N + col] = (OutT)acc[mi][ni][r];
        }
  } else {
    // q-path epilogue: write absorbed Q directly
    bool ropeTile = (n0 >= 256);
#pragma unroll
    for (int mi = 0; mi < 4; mi++)
#pragma unroll
      for (int r = 0; r < 4; r++) {
        int row = m0 + mi * 16 + g * 4 + r;       // token t
        int b = row >> 11, s = row & (S - 1);
#pragma unroll
        for (int ni = 0; ni < 2; ni++) {
          int col = n0 + wid * 32 + ni * 16 + c;
          float val = acc[mi][ni][r];
          if (!ropeTile) {
            int h = col >> 4, cq = col & 15;
            bf16* qrow = Qp + (size_t)((b * 16 + h) * 2048 + s) * 96;
            qrow[64 + cq] = (bf16)(val * KSC);
            qrow[80 + cq] = (bf16)0.f;
          } else {
            int colr = col - 256;
            int h = colr >> 6, jj = colr & 63, j = jj >> 1;
            int pos = pos_ids[row];
            float cf = cos_t[pos * 32 + j], sf = sin_t[pos * 32 + j];
            float other = __shfl_xor(val, 1);
            bf16* qrow = Qp + (size_t)((b * 16 + h) * 2048 + s) * 96;
            if ((c & 1) == 0) {
              qrow[j] = (bf16)((val * cf - other * sf) * KSC);
            } else {
              qrow[32 + j] = (bf16)((val * cf + other * sf) * KSC);
            }
          }
        }
      }
  }
}

// ---------------- absorbed flash attention (round-19 proven layout) ----------------
// 512 blocks: b=lin>>8, u=lin&255; qt = b ? u>>1 : 127-(u>>1) -> each (b,hg,qt) exactly
// once; heavy/light halves anti-correlated; 72KB LDS -> 2 blocks/CU co-resident.
__global__ __launch_bounds__(512, 4) void attn_kernel(
    const bf16* __restrict__ Qp, const bf16* __restrict__ KcG,
    const bf16* __restrict__ cTG, bf16* __restrict__ OC) {
  __shared__ bf16 Kls[128 * 128];     // 32KB
  __shared__ bf16 Cls[2][16 * 128];   // 4KB x2
  __shared__ bf16 Pls[8][16 * 128];   // 4KB per wave

  int lin = blockIdx.x;               // 0..511
  int v = lin >> 8, u = lin & 255;
  int qt = v ? (u >> 1) : (127 - (u >> 1));
  int hg = u & 1, b = v;
  int q0 = qt * 16;
  int nt = qt / 8 + 1;
  int tid = threadIdx.x;
  int w = tid >> 6, lane = tid & 63;
  int g = lane >> 4, cc = lane & 15;
  int h = hg * 8 + w;
  char* pbase = reinterpret_cast<char*>(&Pls[w][0]);

  bf16x8 kst[4];
  auto load_k = [&](int k0) {
#pragma unroll
    for (int i = 0; i < 4; i++) {
      int id = w * 4 + i;
      int key = id * 4 + (lane >> 4);
      int sg = (lane & 15) ^ ((id >> 1) & 15);
      kst[i] = *reinterpret_cast<const bf16x8*>(
          KcG + (((size_t)(b * S + k0 + key)) << 7) + sg * 8);
    }
  };
  auto write_k = [&]() {
#pragma unroll
    for (int i = 0; i < 4; i++) {
      int id = w * 4 + i;
      *reinterpret_cast<bf16x8*>(&Kls[(id * 64 + lane) * 8]) = kst[i];
    }
  };
  auto stage_c = [&](int k0, int buf) {
    if (w >= 4) {
      int c = (w - 4) * 4 + (lane >> 4);
      int sg = (lane & 15) ^ c;
      gload_lds16(cTG + (size_t)(b * 16 + c) * S + k0 + sg * 8,
                  &Cls[buf][(w - 4) * 512]);
    }
  };

  bf16x8 aq[3];
  const bf16* qp = Qp + (size_t)((b * 16 + h) * 2048 + q0 + cc) * 96;
#pragma unroll
  for (int kk = 0; kk < 3; kk++)
    aq[kk] = *reinterpret_cast<const bf16x8*>(qp + kk * 32 + g * 8);

  stage_c(0, 0);
  __builtin_amdgcn_sched_barrier(0);
  load_k(0);
  VMWAIT0;
  write_k();
  if (nt > 1) {
    stage_c(128, 1);
    __builtin_amdgcn_sched_barrier(0);
    load_k(128);
  }
  LGWAIT0;
  __builtin_amdgcn_s_barrier();
  __builtin_amdgcn_sched_barrier(0);

  bf16x8 ones;
#pragma unroll
  for (int j = 0; j < 8; j++) ones[j] = (bf16)1.f;

  f32x4 oc = {}, ls = {};

#pragma unroll 1
  for (int kt = 0; kt < nt; kt++) {
    int cur = kt & 1;
    int k0 = kt * 128;
    f32x4 sacc[8] = {};
    __builtin_amdgcn_s_setprio(1);
#pragma unroll
    for (int kk = 0; kk < 3; kk++)
#pragma unroll
      for (int ntb = 0; ntb < 8; ntb++) {
        int key = cc * 8 + ntb;
        bf16x8 bk = *reinterpret_cast<const bf16x8*>(
            &Kls[(key * 16 + ((kk * 4 + g) ^ cc)) * 8]);
        sacc[ntb] = __builtin_amdgcn_mfma_f32_16x16x32_bf16(aq[kk], bk, sacc[ntb], 0, 0, 0);
      }
    __builtin_amdgcn_s_setprio(0);

    bool diag = (kt == nt - 1);
#pragma unroll
    for (int r = 0; r < 4; r++) {
      bf16x8 pk;
#pragma unroll
      for (int ntb = 0; ntb < 8; ntb++) {
        float x = sacc[ntb][r];
        if (diag) {
          int qr = q0 + g * 4 + r, kc = k0 + cc * 8 + ntb;
          if (kc > qr) x = -1e30f;
        }
        pk[ntb] = (bf16)__builtin_amdgcn_exp2f(x);
      }
      int q = g * 4 + r;
      *reinterpret_cast<bf16x8*>(pbase + (q * 16 + (cc ^ (q & 7))) * 16) = pk;
    }
    LGWAIT0;
    __builtin_amdgcn_s_setprio(1);
#pragma unroll
    for (int kk2 = 0; kk2 < 4; kk2++) {
      bf16x8 pa = *reinterpret_cast<const bf16x8*>(
          pbase + (cc * 16 + ((kk2 * 4 + g) ^ (cc & 7))) * 16);
      bf16x8 bv = *reinterpret_cast<const bf16x8*>(
          &Cls[cur][(cc * 16 + ((kk2 * 4 + g) ^ cc)) * 8]);
      oc = __builtin_amdgcn_mfma_f32_16x16x32_bf16(pa, bv, oc, 0, 0, 0);
      ls = __builtin_amdgcn_mfma_f32_16x16x32_bf16(pa, ones, ls, 0, 0, 0);
    }
    __builtin_amdgcn_s_setprio(0);

    if (kt + 1 < nt) {
      __builtin_amdgcn_s_barrier();
      __builtin_amdgcn_sched_barrier(0);
      VMWAIT0;
      write_k();
      if (kt + 2 < nt) {
        stage_c((kt + 2) * 128, cur);
        __builtin_amdgcn_sched_barrier(0);
        load_k((kt + 2) * 128);
      }
      LGWAIT0;
      __builtin_amdgcn_s_barrier();
      __builtin_amdgcn_sched_barrier(0);
    }
  }

#pragma unroll
  for (int r = 0; r < 4; r++) {
    size_t t = (size_t)b * S + q0 + g * 4 + r;
    OC[t * 256 + h * 16 + cc] = (bf16)(oc[r] / ls[r]);
  }
}

// ---------------- host ----------------
extern "C" void kernel_launch(void* const* d_in, const int* in_sizes, int n_in,
                              void* d_out, int out_size, void* d_ws, size_t ws_size,
                              hipStream_t stream) {
  const float* inputs    = (const float*)d_in[0];
  const int*   pos_ids   = (const int*)d_in[1];
  const float* Wq_down   = (const float*)d_in[3];
  const float* q_norm_w  = (const float*)d_in[4];
  const float* Wq_up     = (const float*)d_in[5];
  const float* Wkv_down  = (const float*)d_in[6];
  const float* kv_norm_w = (const float*)d_in[7];
  const float* Wkv_up    = (const float*)d_in[8];
  const float* Wout      = (const float*)d_in[9];
  float* out = (float*)d_out;

  char* ws = (char*)d_ws;
  size_t off = 0;
  auto alloc = [&](size_t bytes) -> void* {
    void* p = ws + off;
    off += (bytes + 255) & ~(size_t)255;
    return p;
  };

  bf16*  in_bf = (bf16*)alloc((size_t)T * D * 2);
  bf16*  WdT   = (bf16*)alloc((size_t)NDNP * D * 2);
  bf16*  WqxT  = (bf16*)alloc((size_t)NQX * DC_Q * 2);
  bf16*  W2T   = (bf16*)alloc((size_t)D * 256 * 2);
  bf16*  cqkv  = (bf16*)alloc((size_t)T * NDNP * 2);
  bf16*  cqn   = (bf16*)alloc((size_t)T * DC_Q * 2);
  bf16*  KcG   = (bf16*)alloc((size_t)T * 128 * 2);
  bf16*  cTG   = (bf16*)alloc((size_t)B * 16 * S * 2);
  bf16*  Qp    = (bf16*)alloc((size_t)B * H * S * 96 * 2);
  bf16*  OC    = (bf16*)alloc((size_t)T * H * 16 * 2);
  float* cos_t = (float*)alloc((size_t)S * 32 * 4);
  float* sin_t = (float*)alloc((size_t)S * 32 * 4);

  prologue_kernel<<<2832, 256, 0, stream>>>(
      inputs, Wq_down, Wq_up, Wkv_down, Wkv_up, Wout,
      in_bf, WdT, WqxT, W2T, cos_t, sin_t);

  gemm_bt_kernel<bf16, 0><<<dim3(NDNP / 128, T / 64), 256, 0, stream>>>(
      in_bf, WdT, cqkv, T, NDNP, D);
  norm_kv_kernel<<<T / 4, 256, 0, stream>>>(
      cqkv, q_norm_w, kv_norm_w, pos_ids, cos_t, sin_t, cqn, KcG, cTG);
  gemm_bt_kernel<bf16, 1><<<dim3(NQX / 128, T / 64), 256, 0, stream>>>(
      cqn, WqxT, (bf16*)nullptr, T, NQX, DC_Q, pos_ids, cos_t, sin_t, Qp);
  attn_kernel<<<512, 512, 0, stream>>>(Qp, KcG, cTG, OC);
  gemm_bt_kernel<float, 0><<<dim3(D / 128, T / 64), 256, 0, stream>>>(
      OC, W2T, out, T, D, 256);
}

// Round 29
// 127.394 us; speedup vs baseline: 1.0004x; 1.0004x over previous
//
#include <hip/hip_runtime.h>

typedef __bf16 bf16;
typedef __bf16 bf16x8 __attribute__((ext_vector_type(8)));
typedef __bf16 bf16x4 __attribute__((ext_vector_type(4)));
typedef float f32x4 __attribute__((ext_vector_type(4)));

constexpr int D = 2048, H = 16, DPH = 128, DR = 64, DC_KV = 16, DC_Q = 512;
constexpr int QHD = 192, MEG = 256, B = 2, S = 2048;
constexpr int T = B * S;
constexpr int NDNP = 640;   // fused down-proj width (512 q + 80 kv), padded to x128
constexpr int NQX = 1280;   // q gemm width: 256 absorbed qc + 1024 rope
constexpr float EPS = 1e-7f;
constexpr float KSC = 0.104124247f;  // (1/sqrt(192)) * log2(e), folded into Qp

static __device__ __forceinline__ bf16x8 zero8() {
  bf16x8 v;
#pragma unroll
  for (int j = 0; j < 8; j++) v[j] = (bf16)0.f;
  return v;
}

static __device__ __forceinline__ void gload_lds16(const bf16* g, bf16* l) {
  __builtin_amdgcn_global_load_lds(
      (const __attribute__((address_space(1))) unsigned int*)g,
      (__attribute__((address_space(3))) unsigned int*)l, 16, 0, 0);
}

#define LGWAIT0 do { asm volatile("s_waitcnt lgkmcnt(0)" ::: "memory"); __builtin_amdgcn_sched_barrier(0); } while (0)
#define VMWAIT0 do { asm volatile("s_waitcnt vmcnt(0)" ::: "memory"); __builtin_amdgcn_sched_barrier(0); } while (0)

// ================= mega prologue: all input-independent prep in ONE launch =================
// All write regions are pairwise DISJOINT (no inter-block ordering needed):
// blocks [0,32)        : prep_w3 -> WqxT rows [0,256)    (256 thr, v-loop unroll 8)
// blocks [32,160)      : prep_w2 -> W2T                  (256 thr, v-loop unroll 8)
// blocks [160,288)     : prep_wrope -> WqxT rows [256,1280)
// blocks [288,1312)    : transpose Wq_down -> WdT rows [0,512)
// blocks [1312,1504)   : transpose Wkv_down -> WdT rows [512,592)
// blocks [1504,1552)   : zero WdT pad rows [592,640)
// blocks [1552,1808)   : rope table (f32, matches f32 jnp reference)
// blocks [1808,2832)   : cast inputs f32 -> in_bf (8 float4/thread, batched loads)
__global__ __launch_bounds__(256) void prologue_kernel(
    const float* __restrict__ inputs, const float* __restrict__ Wq_down,
    const float* __restrict__ Wq_up, const float* __restrict__ Wkv_down,
    const float* __restrict__ Wkv_up, const float* __restrict__ Wout,
    bf16* __restrict__ in_bf, bf16* __restrict__ WdT, bf16* __restrict__ WqxT,
    bf16* __restrict__ W2T, float* __restrict__ cos_t, float* __restrict__ sin_t) {
  __shared__ float smem[64 * 65];
  int bid = blockIdx.x;
  int tid = threadIdx.x;

  if (bid < 32) {                         // ---- prep_w3 (all 256 threads) ----
    int h = bid >> 1, k0 = (bid & 1) * 256;
    float (*wk)[16] = (float(*)[16])smem;
#pragma unroll
    for (int e = tid; e < 2048; e += 256) {
      int v = e >> 4, c = e & 15;
      wk[v][c] = Wkv_up[(size_t)c * (H * MEG) + h * MEG + v];
    }
    __syncthreads();
    int k = k0 + tid;
    float acc[16] = {};
#pragma unroll 8
    for (int v = 0; v < 128; v++) {
      float wq = Wq_up[(size_t)k * (H * QHD) + h * QHD + v];
#pragma unroll
      for (int c = 0; c < 16; c++) acc[c] += wk[v][c] * wq;
    }
#pragma unroll
    for (int c = 0; c < 16; c++)
      WqxT[(size_t)(h * 16 + c) * DC_Q + k] = (bf16)acc[c];
  } else if (bid < 160) {                 // ---- prep_w2 (all 256 threads) ----
    int lb = bid - 32;
    int h = lb >> 3, d0 = (lb & 7) * 256;
    float (*wv)[16] = (float(*)[16])smem;
#pragma unroll
    for (int e = tid; e < 2048; e += 256) {
      int v = e >> 4, c = e & 15;
      wv[v][c] = Wkv_up[(size_t)c * (H * MEG) + h * MEG + 128 + v];
    }
    __syncthreads();
    int d = d0 + tid;
    float acc[16] = {};
#pragma unroll 8
    for (int v = 0; v < 128; v++) {
      float wo = Wout[(size_t)(h * 128 + v) * D + d];
#pragma unroll
      for (int c = 0; c < 16; c++) acc[c] += wv[v][c] * wo;
    }
    bf16x8 o0, o1;
#pragma unroll
    for (int c = 0; c < 8; c++) { o0[c] = (bf16)acc[c]; o1[c] = (bf16)acc[8 + c]; }
    *reinterpret_cast<bf16x8*>(&W2T[(size_t)d * 256 + h * 16]) = o0;
    *reinterpret_cast<bf16x8*>(&W2T[(size_t)d * 256 + h * 16 + 8]) = o1;
  } else if (bid < 288) {                 // ---- prep_wrope ----
    int lb = bid - 160;
    int h = lb >> 3, k0 = (lb & 7) * 64;
    float (*tile)[65] = (float(*)[65])smem;
#pragma unroll
    for (int p = 0; p < 16; p++) {
      int kk = p * 4 + (tid >> 6), j = tid & 63;
      tile[kk][j] = Wq_up[(size_t)(k0 + kk) * (H * QHD) + h * QHD + 128 + j];
    }
    __syncthreads();
#pragma unroll
    for (int p = 0; p < 16; p++) {
      int n = p * 4 + (tid >> 6), k = tid & 63;
      WqxT[(size_t)(256 + h * 64 + n) * DC_Q + k0 + k] = (bf16)tile[k][n];
    }
  } else if (bid < 1504) {                // ---- transposes ----
    const float* src; bf16* dst; int K, N, k0, n0;
    if (bid < 1312) {
      int lb = bid - 288;
      src = Wq_down; dst = WdT; K = D; N = DC_Q;
      k0 = (lb >> 4) * 32; n0 = (lb & 15) * 32;
    } else {
      int lb = bid - 1312;
      src = Wkv_down; dst = WdT + (size_t)DC_Q * D; K = D; N = 80;
      k0 = (lb / 3) * 32; n0 = (lb % 3) * 32;
    }
    float (*tile)[33] = (float(*)[33])smem;
#pragma unroll
    for (int e = tid; e < 1024; e += 256) {
      int i = e >> 5, j = e & 31;
      int k = k0 + i, n = n0 + j;
      tile[i][j] = (k < K && n < N) ? src[(size_t)k * N + n] : 0.f;
    }
    __syncthreads();
#pragma unroll
    for (int e = tid; e < 1024; e += 256) {
      int jj = e >> 5, ii = e & 31;
      int n = n0 + jj, k = k0 + ii;
      if (k < K && n < N) dst[(size_t)n * D + k] = (bf16)tile[ii][jj];
    }
  } else if (bid < 1552) {                // ---- zero WdT pad rows only ----
    size_t i = (size_t)592 * D + ((size_t)(bid - 1504) * 256 + tid) * 8;
    *reinterpret_cast<bf16x8*>(WdT + i) = zero8();
  } else if (bid < 1808) {                // ---- rope table (f32) ----
    int i = (bid - 1552) * 256 + tid;     // over S*32
    int pos = i >> 5, j = i & 31;
    float invf = 1.0f / powf(10000.0f, (float)(2 * j) / 64.0f);
    float a = (float)pos * invf;
    cos_t[i] = cosf(a);
    sin_t[i] = sinf(a);
  } else {                                // ---- cast (8 rounds, batched loads) ----
    int gid = (bid - 1808) * 256 + tid;   // float4 index, 262144 per round
    float4 v[8];
#pragma unroll
    for (int k = 0; k < 8; k++)
      v[k] = *reinterpret_cast<const float4*>(inputs + ((size_t)(gid + k * 262144)) * 4);
#pragma unroll
    for (int k = 0; k < 8; k++) {
      bf16x4 o;
      o[0] = (bf16)v[k].x; o[1] = (bf16)v[k].y; o[2] = (bf16)v[k].z; o[3] = (bf16)v[k].w;
      *reinterpret_cast<bf16x4*>(in_bf + ((size_t)(gid + k * 262144)) * 4) = o;
    }
  }
}

// ======== merged rmsnorm(q) + kv prep: 1 wave per token; cqkv is bf16 ========
__global__ __launch_bounds__(256) void norm_kv_kernel(
    const bf16* __restrict__ cqkv, const float* __restrict__ qw,
    const float* __restrict__ kvw, const int* __restrict__ pos_ids,
    const float* __restrict__ cos_t, const float* __restrict__ sin_t,
    bf16* __restrict__ cqn, bf16* __restrict__ KcG, bf16* __restrict__ cTG) {
  int w = threadIdx.x >> 6, lane = threadIdx.x & 63;
  int t = blockIdx.x * 4 + w;
  int b = t >> 11, s = t & (S - 1);
  const bf16* x = cqkv + (size_t)t * NDNP;
  // ---- q rmsnorm over [0,512) ----
  bf16x8 xv = *reinterpret_cast<const bf16x8*>(x + lane * 8);
  float vv[8];
  float ss = 0.f;
#pragma unroll
  for (int j = 0; j < 8; j++) { vv[j] = (float)xv[j]; ss += vv[j] * vv[j]; }
#pragma unroll
  for (int off = 32; off; off >>= 1) ss += __shfl_xor(ss, off);
  float r = rsqrtf(ss / (float)DC_Q + EPS);
  const float* wp = qw + lane * 8;
  bf16x8 o;
#pragma unroll
  for (int j = 0; j < 8; j++) o[j] = (bf16)(vv[j] * r * wp[j]);
  *reinterpret_cast<bf16x8*>(cqn + (size_t)t * DC_Q + lane * 8) = o;
  // ---- kv prep over [512,592) ----
  const bf16* xk = x + DC_Q;
  float vk = (lane < 16) ? (float)xk[lane] : 0.f;
  float sk = vk * vk;
#pragma unroll
  for (int off = 1; off < 16; off <<= 1) sk += __shfl_xor(sk, off);
  float rk = rsqrtf(sk / 16.f + EPS);
  bf16* krow = KcG + ((size_t)t << 7);
  if (lane < 16) {
    bf16 cn = (bf16)(vk * rk * kvw[lane]);
    krow[64 + lane] = cn;
    cTG[(size_t)(b * 16 + lane) * S + s] = cn;
  } else {
    krow[64 + lane] = (bf16)0.f;   // dims 80..127 zero
  }
  if (lane < 32) {
    int j = lane;
    int pos = pos_ids[t];
    float cf = cos_t[pos * 32 + j], sf = sin_t[pos * 32 + j];
    float x0 = (float)xk[16 + 2 * j], x1 = (float)xk[16 + 2 * j + 1];
    krow[j]      = (bf16)(x0 * cf - x1 * sf);
    krow[32 + j] = (bf16)(x1 * cf + x0 * sf);
  }
}

// ---------------- bf16 MFMA GEMM, 64x128 tile, dbuf + counted vmcnt ----------------
template <typename OutT, int EPI>
__global__ __launch_bounds__(256) void gemm_bt_kernel(
    const bf16* __restrict__ A, const bf16* __restrict__ Bt,
    OutT* __restrict__ C, int M, int N, int K,
    const int* __restrict__ pos_ids = nullptr,
    const float* __restrict__ cos_t = nullptr,
    const float* __restrict__ sin_t = nullptr,
    bf16* __restrict__ Qp = nullptr) {
  __shared__ bf16 As[2][64 * 64];
  __shared__ bf16 Bs[2][128 * 64];
  int tid = threadIdx.x;
  int wid = tid >> 6, lane = tid & 63;
  int g = lane >> 4, c = lane & 15;
  int nbx = gridDim.x;                 // N / 128
  int lin = blockIdx.y * nbx + blockIdx.x;
  int cpx = (nbx * gridDim.y) >> 3;    // grid % 8 == 0 for all uses
  int swz = (lin & 7) * cpx + (lin >> 3);
  int m0 = (swz / nbx) * 64, n0 = (swz % nbx) * 128;
  int lrow8 = tid >> 3, lslot = tid & 7;

  auto stage = [&](int kt, int buf) {
    int k0 = kt << 6;
#pragma unroll
    for (int r = 0; r < 2; r++) {
      int row = r * 32 + lrow8;
      int sslot = lslot ^ (row & 7);
      gload_lds16(A + (size_t)(m0 + row) * K + k0 + sslot * 8, &As[buf][row * 64 + lslot * 8]);
    }
#pragma unroll
    for (int r = 0; r < 4; r++) {
      int row = r * 32 + lrow8;
      int sslot = lslot ^ (row & 7);
      gload_lds16(Bt + (size_t)(n0 + row) * K + k0 + sslot * 8, &Bs[buf][row * 64 + lslot * 8]);
    }
  };

  f32x4 acc[4][2] = {};
  int nk = K >> 6;
  stage(0, 0);
  __builtin_amdgcn_sched_barrier(0);
  for (int kt = 0; kt < nk; kt++) {
    int cur = kt & 1;
    __builtin_amdgcn_s_barrier();
    __builtin_amdgcn_sched_barrier(0);
    if (kt + 1 < nk) {
      stage(kt + 1, cur ^ 1);
      asm volatile("s_waitcnt vmcnt(6)" ::: "memory");
    } else {
      asm volatile("s_waitcnt vmcnt(0)" ::: "memory");
    }
    __builtin_amdgcn_sched_barrier(0);
    __builtin_amdgcn_s_barrier();
    __builtin_amdgcn_sched_barrier(0);
#pragma unroll
    for (int kk = 0; kk < 2; kk++) {
      bf16x8 af[4], bfr[2];
#pragma unroll
      for (int mi = 0; mi < 4; mi++) {
        int row = mi * 16 + c;
        int sl = (kk * 4 + g) ^ (row & 7);
        af[mi] = *reinterpret_cast<const bf16x8*>(&As[cur][row * 64 + sl * 8]);
      }
#pragma unroll
      for (int ni = 0; ni < 2; ni++) {
        int row = wid * 32 + ni * 16 + c;
        int sl = (kk * 4 + g) ^ (row & 7);
        bfr[ni] = *reinterpret_cast<const bf16x8*>(&Bs[cur][row * 64 + sl * 8]);
      }
#pragma unroll
      for (int mi = 0; mi < 4; mi++)
#pragma unroll
        for (int ni = 0; ni < 2; ni++)
          acc[mi][ni] = __builtin_amdgcn_mfma_f32_16x16x32_bf16(af[mi], bfr[ni], acc[mi][ni], 0, 0, 0);
    }
  }

  if constexpr (EPI == 0) {
#pragma unroll
    for (int mi = 0; mi < 4; mi++)
#pragma unroll
      for (int ni = 0; ni < 2; ni++)
#pragma unroll
        for (int r = 0; r < 4; r++) {
          int row = m0 + mi * 16 + g * 4 + r;
          int col = n0 + wid * 32 + ni * 16 + c;
          C[(size_t)row * N + col] = (OutT)acc[mi][ni][r];
        }
  } else {
    // q-path epilogue: write absorbed Q directly
    bool ropeTile = (n0 >= 256);
#pragma unroll
    for (int mi = 0; mi < 4; mi++)
#pragma unroll
      for (int r = 0; r < 4; r++) {
        int row = m0 + mi * 16 + g * 4 + r;       // token t
        int b = row >> 11, s = row & (S - 1);
#pragma unroll
        for (int ni = 0; ni < 2; ni++) {
          int col = n0 + wid * 32 + ni * 16 + c;
          float val = acc[mi][ni][r];
          if (!ropeTile) {
            int h = col >> 4, cq = col & 15;
            bf16* qrow = Qp + (size_t)((b * 16 + h) * 2048 + s) * 96;
            qrow[64 + cq] = (bf16)(val * KSC);
            qrow[80 + cq] = (bf16)0.f;
          } else {
            int colr = col - 256;
            int h = colr >> 6, jj = colr & 63, j = jj >> 1;
            int pos = pos_ids[row];
            float cf = cos_t[pos * 32 + j], sf = sin_t[pos * 32 + j];
            float other = __shfl_xor(val, 1);
            bf16* qrow = Qp + (size_t)((b * 16 + h) * 2048 + s) * 96;
            if ((c & 1) == 0) {
              qrow[j] = (bf16)((val * cf - other * sf) * KSC);
            } else {
              qrow[32 + j] = (bf16)((val * cf + other * sf) * KSC);
            }
          }
        }
      }
  }
}

// ---------------- absorbed flash attention (round-19 proven layout) ----------------
// 512 blocks: b=lin>>8, u=lin&255; qt = b ? u>>1 : 127-(u>>1) -> each (b,hg,qt) exactly
// once; heavy/light halves anti-correlated; 72KB LDS -> 2 blocks/CU co-resident.
__global__ __launch_bounds__(512, 4) void attn_kernel(
    const bf16* __restrict__ Qp, const bf16* __restrict__ KcG,
    const bf16* __restrict__ cTG, bf16* __restrict__ OC) {
  __shared__ bf16 Kls[128 * 128];     // 32KB
  __shared__ bf16 Cls[2][16 * 128];   // 4KB x2
  __shared__ bf16 Pls[8][16 * 128];   // 4KB per wave

  int lin = blockIdx.x;               // 0..511
  int v = lin >> 8, u = lin & 255;
  int qt = v ? (u >> 1) : (127 - (u >> 1));
  int hg = u & 1, b = v;
  int q0 = qt * 16;
  int nt = qt / 8 + 1;
  int tid = threadIdx.x;
  int w = tid >> 6, lane = tid & 63;
  int g = lane >> 4, cc = lane & 15;
  int h = hg * 8 + w;
  char* pbase = reinterpret_cast<char*>(&Pls[w][0]);

  bf16x8 kst[4];
  auto load_k = [&](int k0) {
#pragma unroll
    for (int i = 0; i < 4; i++) {
      int id = w * 4 + i;
      int key = id * 4 + (lane >> 4);
      int sg = (lane & 15) ^ ((id >> 1) & 15);
      kst[i] = *reinterpret_cast<const bf16x8*>(
          KcG + (((size_t)(b * S + k0 + key)) << 7) + sg * 8);
    }
  };
  auto write_k = [&]() {
#pragma unroll
    for (int i = 0; i < 4; i++) {
      int id = w * 4 + i;
      *reinterpret_cast<bf16x8*>(&Kls[(id * 64 + lane) * 8]) = kst[i];
    }
  };
  auto stage_c = [&](int k0, int buf) {
    if (w >= 4) {
      int c = (w - 4) * 4 + (lane >> 4);
      int sg = (lane & 15) ^ c;
      gload_lds16(cTG + (size_t)(b * 16 + c) * S + k0 + sg * 8,
                  &Cls[buf][(w - 4) * 512]);
    }
  };

  bf16x8 aq[3];
  const bf16* qp = Qp + (size_t)((b * 16 + h) * 2048 + q0 + cc) * 96;
#pragma unroll
  for (int kk = 0; kk < 3; kk++)
    aq[kk] = *reinterpret_cast<const bf16x8*>(qp + kk * 32 + g * 8);

  stage_c(0, 0);
  __builtin_amdgcn_sched_barrier(0);
  load_k(0);
  VMWAIT0;
  write_k();
  if (nt > 1) {
    stage_c(128, 1);
    __builtin_amdgcn_sched_barrier(0);
    load_k(128);
  }
  LGWAIT0;
  __builtin_amdgcn_s_barrier();
  __builtin_amdgcn_sched_barrier(0);

  bf16x8 ones;
#pragma unroll
  for (int j = 0; j < 8; j++) ones[j] = (bf16)1.f;

  f32x4 oc = {}, ls = {};

#pragma unroll 1
  for (int kt = 0; kt < nt; kt++) {
    int cur = kt & 1;
    int k0 = kt * 128;
    f32x4 sacc[8] = {};
    __builtin_amdgcn_s_setprio(1);
#pragma unroll
    for (int kk = 0; kk < 3; kk++)
#pragma unroll
      for (int ntb = 0; ntb < 8; ntb++) {
        int key = cc * 8 + ntb;
        bf16x8 bk = *reinterpret_cast<const bf16x8*>(
            &Kls[(key * 16 + ((kk * 4 + g) ^ cc)) * 8]);
        sacc[ntb] = __builtin_amdgcn_mfma_f32_16x16x32_bf16(aq[kk], bk, sacc[ntb], 0, 0, 0);
      }
    __builtin_amdgcn_s_setprio(0);

    bool diag = (kt == nt - 1);
#pragma unroll
    for (int r = 0; r < 4; r++) {
      bf16x8 pk;
#pragma unroll
      for (int ntb = 0; ntb < 8; ntb++) {
        float x = sacc[ntb][r];
        if (diag) {
          int qr = q0 + g * 4 + r, kc = k0 + cc * 8 + ntb;
          if (kc > qr) x = -1e30f;
        }
        pk[ntb] = (bf16)__builtin_amdgcn_exp2f(x);
      }
      int q = g * 4 + r;
      *reinterpret_cast<bf16x8*>(pbase + (q * 16 + (cc ^ (q & 7))) * 16) = pk;
    }
    LGWAIT0;
    __builtin_amdgcn_s_setprio(1);
#pragma unroll
    for (int kk2 = 0; kk2 < 4; kk2++) {
      bf16x8 pa = *reinterpret_cast<const bf16x8*>(
          pbase + (cc * 16 + ((kk2 * 4 + g) ^ (cc & 7))) * 16);
      bf16x8 bv = *reinterpret_cast<const bf16x8*>(
          &Cls[cur][(cc * 16 + ((kk2 * 4 + g) ^ cc)) * 8]);
      oc = __builtin_amdgcn_mfma_f32_16x16x32_bf16(pa, bv, oc, 0, 0, 0);
      ls = __builtin_amdgcn_mfma_f32_16x16x32_bf16(pa, ones, ls, 0, 0, 0);
    }
    __builtin_amdgcn_s_setprio(0);

    if (kt + 1 < nt) {
      __builtin_amdgcn_s_barrier();
      __builtin_amdgcn_sched_barrier(0);
      VMWAIT0;
      write_k();
      if (kt + 2 < nt) {
        stage_c((kt + 2) * 128, cur);
        __builtin_amdgcn_sched_barrier(0);
        load_k((kt + 2) * 128);
      }
      LGWAIT0;
      __builtin_amdgcn_s_barrier();
      __builtin_amdgcn_sched_barrier(0);
    }
  }

#pragma unroll
  for (int r = 0; r < 4; r++) {
    size_t t = (size_t)b * S + q0 + g * 4 + r;
    OC[t * 256 + h * 16 + cc] = (bf16)(oc[r] / ls[r]);
  }
}

// ---------------- host ----------------
extern "C" void kernel_launch(void* const* d_in, const int* in_sizes, int n_in,
                              void* d_out, int out_size, void* d_ws, size_t ws_size,
                              hipStream_t stream) {
  const float* inputs    = (const float*)d_in[0];
  const int*   pos_ids   = (const int*)d_in[1];
  const float* Wq_down   = (const float*)d_in[3];
  const float* q_norm_w  = (const float*)d_in[4];
  const float* Wq_up     = (const float*)d_in[5];
  const float* Wkv_down  = (const float*)d_in[6];
  const float* kv_norm_w = (const float*)d_in[7];
  const float* Wkv_up    = (const float*)d_in[8];
  const float* Wout      = (const float*)d_in[9];
  float* out = (float*)d_out;

  char* ws = (char*)d_ws;
  size_t off = 0;
  auto alloc = [&](size_t bytes) -> void* {
    void* p = ws + off;
    off += (bytes + 255) & ~(size_t)255;
    return p;
  };

  bf16*  in_bf = (bf16*)alloc((size_t)T * D * 2);
  bf16*  WdT   = (bf16*)alloc((size_t)NDNP * D * 2);
  bf16*  WqxT  = (bf16*)alloc((size_t)NQX * DC_Q * 2);
  bf16*  W2T   = (bf16*)alloc((size_t)D * 256 * 2);
  bf16*  cqkv  = (bf16*)alloc((size_t)T * NDNP * 2);
  bf16*  cqn   = (bf16*)alloc((size_t)T * DC_Q * 2);
  bf16*  KcG   = (bf16*)alloc((size_t)T * 128 * 2);
  bf16*  cTG   = (bf16*)alloc((size_t)B * 16 * S * 2);
  bf16*  Qp    = (bf16*)alloc((size_t)B * H * S * 96 * 2);
  bf16*  OC    = (bf16*)alloc((size_t)T * H * 16 * 2);
  float* cos_t = (float*)alloc((size_t)S * 32 * 4);
  float* sin_t = (float*)alloc((size_t)S * 32 * 4);

  prologue_kernel<<<2832, 256, 0, stream>>>(
      inputs, Wq_down, Wq_up, Wkv_down, Wkv_up, Wout,
      in_bf, WdT, WqxT, W2T, cos_t, sin_t);

  gemm_bt_kernel<bf16, 0><<<dim3(NDNP / 128, T / 64), 256, 0, stream>>>(
      in_bf, WdT, cqkv, T, NDNP, D);
  norm_kv_kernel<<<T / 4, 256, 0, stream>>>(
      cqkv, q_norm_w, kv_norm_w, pos_ids, cos_t, sin_t, cqn, KcG, cTG);
  gemm_bt_kernel<bf16, 1><<<dim3(NQX / 128, T / 64), 256, 0, stream>>>(
      cqn, WqxT, (bf16*)nullptr, T, NQX, DC_Q, pos_ids, cos_t, sin_t, Qp);
  attn_kernel<<<512, 512, 0, stream>>>(Qp, KcG, cTG, OC);
  gemm_bt_kernel<float, 0><<<dim3(D / 128, T / 64), 256, 0, stream>>>(
      OC, W2T, out, T, D, 256);
}

// Round 30
// 126.863 us; speedup vs baseline: 1.0046x; 1.0042x over previous
//
#include <hip/hip_runtime.h>

typedef __bf16 bf16;
typedef __bf16 bf16x8 __attribute__((ext_vector_type(8)));
typedef __bf16 bf16x4 __attribute__((ext_vector_type(4)));
typedef float f32x4 __attribute__((ext_vector_type(4)));

constexpr int D = 2048, H = 16, DPH = 128, DR = 64, DC_KV = 16, DC_Q = 512;
constexpr int QHD = 192, MEG = 256, B = 2, S = 2048;
constexpr int T = B * S;
constexpr int NDNP = 640;   // fused down-proj width (512 q + 80 kv), padded to x128
constexpr int NQX = 1280;   // q gemm width: 256 absorbed qc + 1024 rope
constexpr float EPS = 1e-7f;
constexpr float KSC = 0.104124247f;  // (1/sqrt(192)) * log2(e), folded into Qp

static __device__ __forceinline__ bf16x8 zero8() {
  bf16x8 v;
#pragma unroll
  for (int j = 0; j < 8; j++) v[j] = (bf16)0.f;
  return v;
}

static __device__ __forceinline__ void gload_lds16(const bf16* g, bf16* l) {
  __builtin_amdgcn_global_load_lds(
      (const __attribute__((address_space(1))) unsigned int*)g,
      (__attribute__((address_space(3))) unsigned int*)l, 16, 0, 0);
}

#define LGWAIT0 do { asm volatile("s_waitcnt lgkmcnt(0)" ::: "memory"); __builtin_amdgcn_sched_barrier(0); } while (0)
#define VMWAIT0 do { asm volatile("s_waitcnt vmcnt(0)" ::: "memory"); __builtin_amdgcn_sched_barrier(0); } while (0)

// ================= mega prologue: all input-independent prep in ONE launch =================
// All write regions are pairwise DISJOINT (no inter-block ordering needed):
// blocks [0,32)        : prep_w3 -> WqxT rows [0,256)    (256 thr, v-loop unroll 8)
// blocks [32,160)      : prep_w2 -> W2T                  (256 thr, v-loop unroll 8)
// blocks [160,288)     : prep_wrope -> WqxT rows [256,1280)
// blocks [288,1312)    : transpose Wq_down -> WdT rows [0,512)
// blocks [1312,1504)   : transpose Wkv_down -> WdT rows [512,592)
// blocks [1504,1552)   : zero WdT pad rows [592,640)
// blocks [1552,1808)   : rope table (f32, matches f32 jnp reference)
// blocks [1808,2832)   : cast inputs f32 -> in_bf (8 float4/thread, batched loads)
__global__ __launch_bounds__(256) void prologue_kernel(
    const float* __restrict__ inputs, const float* __restrict__ Wq_down,
    const float* __restrict__ Wq_up, const float* __restrict__ Wkv_down,
    const float* __restrict__ Wkv_up, const float* __restrict__ Wout,
    bf16* __restrict__ in_bf, bf16* __restrict__ WdT, bf16* __restrict__ WqxT,
    bf16* __restrict__ W2T, float* __restrict__ cos_t, float* __restrict__ sin_t) {
  __shared__ float smem[64 * 65];
  int bid = blockIdx.x;
  int tid = threadIdx.x;

  if (bid < 32) {                         // ---- prep_w3 (all 256 threads) ----
    int h = bid >> 1, k0 = (bid & 1) * 256;
    float (*wk)[16] = (float(*)[16])smem;
#pragma unroll
    for (int e = tid; e < 2048; e += 256) {
      int v = e >> 4, c = e & 15;
      wk[v][c] = Wkv_up[(size_t)c * (H * MEG) + h * MEG + v];
    }
    __syncthreads();
    int k = k0 + tid;
    float acc[16] = {};
#pragma unroll 8
    for (int v = 0; v < 128; v++) {
      float wq = Wq_up[(size_t)k * (H * QHD) + h * QHD + v];
#pragma unroll
      for (int c = 0; c < 16; c++) acc[c] += wk[v][c] * wq;
    }
#pragma unroll
    for (int c = 0; c < 16; c++)
      WqxT[(size_t)(h * 16 + c) * DC_Q + k] = (bf16)acc[c];
  } else if (bid < 160) {                 // ---- prep_w2 (all 256 threads) ----
    int lb = bid - 32;
    int h = lb >> 3, d0 = (lb & 7) * 256;
    float (*wv)[16] = (float(*)[16])smem;
#pragma unroll
    for (int e = tid; e < 2048; e += 256) {
      int v = e >> 4, c = e & 15;
      wv[v][c] = Wkv_up[(size_t)c * (H * MEG) + h * MEG + 128 + v];
    }
    __syncthreads();
    int d = d0 + tid;
    float acc[16] = {};
#pragma unroll 8
    for (int v = 0; v < 128; v++) {
      float wo = Wout[(size_t)(h * 128 + v) * D + d];
#pragma unroll
      for (int c = 0; c < 16; c++) acc[c] += wv[v][c] * wo;
    }
    bf16x8 o0, o1;
#pragma unroll
    for (int c = 0; c < 8; c++) { o0[c] = (bf16)acc[c]; o1[c] = (bf16)acc[8 + c]; }
    *reinterpret_cast<bf16x8*>(&W2T[(size_t)d * 256 + h * 16]) = o0;
    *reinterpret_cast<bf16x8*>(&W2T[(size_t)d * 256 + h * 16 + 8]) = o1;
  } else if (bid < 288) {                 // ---- prep_wrope ----
    int lb = bid - 160;
    int h = lb >> 3, k0 = (lb & 7) * 64;
    float (*tile)[65] = (float(*)[65])smem;
#pragma unroll
    for (int p = 0; p < 16; p++) {
      int kk = p * 4 + (tid >> 6), j = tid & 63;
      tile[kk][j] = Wq_up[(size_t)(k0 + kk) * (H * QHD) + h * QHD + 128 + j];
    }
    __syncthreads();
#pragma unroll
    for (int p = 0; p < 16; p++) {
      int n = p * 4 + (tid >> 6), k = tid & 63;
      WqxT[(size_t)(256 + h * 64 + n) * DC_Q + k0 + k] = (bf16)tile[k][n];
    }
  } else if (bid < 1504) {                // ---- transposes ----
    const float* src; bf16* dst; int K, N, k0, n0;
    if (bid < 1312) {
      int lb = bid - 288;
      src = Wq_down; dst = WdT; K = D; N = DC_Q;
      k0 = (lb >> 4) * 32; n0 = (lb & 15) * 32;
    } else {
      int lb = bid - 1312;
      src = Wkv_down; dst = WdT + (size_t)DC_Q * D; K = D; N = 80;
      k0 = (lb / 3) * 32; n0 = (lb % 3) * 32;
    }
    float (*tile)[33] = (float(*)[33])smem;
#pragma unroll
    for (int e = tid; e < 1024; e += 256) {
      int i = e >> 5, j = e & 31;
      int k = k0 + i, n = n0 + j;
      tile[i][j] = (k < K && n < N) ? src[(size_t)k * N + n] : 0.f;
    }
    __syncthreads();
#pragma unroll
    for (int e = tid; e < 1024; e += 256) {
      int jj = e >> 5, ii = e & 31;
      int n = n0 + jj, k = k0 + ii;
      if (k < K && n < N) dst[(size_t)n * D + k] = (bf16)tile[ii][jj];
    }
  } else if (bid < 1552) {                // ---- zero WdT pad rows only ----
    size_t i = (size_t)592 * D + ((size_t)(bid - 1504) * 256 + tid) * 8;
    *reinterpret_cast<bf16x8*>(WdT + i) = zero8();
  } else if (bid < 1808) {                // ---- rope table (f32) ----
    int i = (bid - 1552) * 256 + tid;     // over S*32
    int pos = i >> 5, j = i & 31;
    float invf = 1.0f / powf(10000.0f, (float)(2 * j) / 64.0f);
    float a = (float)pos * invf;
    cos_t[i] = cosf(a);
    sin_t[i] = sinf(a);
  } else {                                // ---- cast (8 rounds, batched loads) ----
    int gid = (bid - 1808) * 256 + tid;   // float4 index, 262144 per round
    float4 v[8];
#pragma unroll
    for (int k = 0; k < 8; k++)
      v[k] = *reinterpret_cast<const float4*>(inputs + ((size_t)(gid + k * 262144)) * 4);
#pragma unroll
    for (int k = 0; k < 8; k++) {
      bf16x4 o;
      o[0] = (bf16)v[k].x; o[1] = (bf16)v[k].y; o[2] = (bf16)v[k].z; o[3] = (bf16)v[k].w;
      *reinterpret_cast<bf16x4*>(in_bf + ((size_t)(gid + k * 262144)) * 4) = o;
    }
  }
}

// ======== merged rmsnorm(q) + kv prep: 1 wave per token; cqkv is bf16 ========
__global__ __launch_bounds__(256) void norm_kv_kernel(
    const bf16* __restrict__ cqkv, const float* __restrict__ qw,
    const float* __restrict__ kvw, const int* __restrict__ pos_ids,
    const float* __restrict__ cos_t, const float* __restrict__ sin_t,
    bf16* __restrict__ cqn, bf16* __restrict__ KcG, bf16* __restrict__ cTG) {
  int w = threadIdx.x >> 6, lane = threadIdx.x & 63;
  int t = blockIdx.x * 4 + w;
  int b = t >> 11, s = t & (S - 1);
  const bf16* x = cqkv + (size_t)t * NDNP;
  // ---- q rmsnorm over [0,512) ----
  bf16x8 xv = *reinterpret_cast<const bf16x8*>(x + lane * 8);
  float vv[8];
  float ss = 0.f;
#pragma unroll
  for (int j = 0; j < 8; j++) { vv[j] = (float)xv[j]; ss += vv[j] * vv[j]; }
#pragma unroll
  for (int off = 32; off; off >>= 1) ss += __shfl_xor(ss, off);
  float r = rsqrtf(ss / (float)DC_Q + EPS);
  const float* wp = qw + lane * 8;
  bf16x8 o;
#pragma unroll
  for (int j = 0; j < 8; j++) o[j] = (bf16)(vv[j] * r * wp[j]);
  *reinterpret_cast<bf16x8*>(cqn + (size_t)t * DC_Q + lane * 8) = o;
  // ---- kv prep over [512,592) ----
  const bf16* xk = x + DC_Q;
  float vk = (lane < 16) ? (float)xk[lane] : 0.f;
  float sk = vk * vk;
#pragma unroll
  for (int off = 1; off < 16; off <<= 1) sk += __shfl_xor(sk, off);
  float rk = rsqrtf(sk / 16.f + EPS);
  bf16* krow = KcG + ((size_t)t << 7);
  if (lane < 16) {
    bf16 cn = (bf16)(vk * rk * kvw[lane]);
    krow[64 + lane] = cn;
    cTG[(size_t)(b * 16 + lane) * S + s] = cn;
  } else {
    krow[64 + lane] = (bf16)0.f;   // dims 80..127 zero
  }
  if (lane < 32) {
    int j = lane;
    int pos = pos_ids[t];
    float cf = cos_t[pos * 32 + j], sf = sin_t[pos * 32 + j];
    float x0 = (float)xk[16 + 2 * j], x1 = (float)xk[16 + 2 * j + 1];
    krow[j]      = (bf16)(x0 * cf - x1 * sf);
    krow[32 + j] = (bf16)(x1 * cf + x0 * sf);
  }
}

// ---------------- bf16 MFMA GEMM, 64x128 tile, dbuf + counted vmcnt ----------------
template <typename OutT, int EPI>
__global__ __launch_bounds__(256) void gemm_bt_kernel(
    const bf16* __restrict__ A, const bf16* __restrict__ Bt,
    OutT* __restrict__ C, int M, int N, int K,
    const int* __restrict__ pos_ids = nullptr,
    const float* __restrict__ cos_t = nullptr,
    const float* __restrict__ sin_t = nullptr,
    bf16* __restrict__ Qp = nullptr) {
  __shared__ bf16 As[2][64 * 64];
  __shared__ bf16 Bs[2][128 * 64];
  int tid = threadIdx.x;
  int wid = tid >> 6, lane = tid & 63;
  int g = lane >> 4, c = lane & 15;
  int nbx = gridDim.x;                 // N / 128
  int lin = blockIdx.y * nbx + blockIdx.x;
  int cpx = (nbx * gridDim.y) >> 3;    // grid % 8 == 0 for all uses
  int swz = (lin & 7) * cpx + (lin >> 3);
  int m0 = (swz / nbx) * 64, n0 = (swz % nbx) * 128;
  int lrow8 = tid >> 3, lslot = tid & 7;

  auto stage = [&](int kt, int buf) {
    int k0 = kt << 6;
#pragma unroll
    for (int r = 0; r < 2; r++) {
      int row = r * 32 + lrow8;
      int sslot = lslot ^ (row & 7);
      gload_lds16(A + (size_t)(m0 + row) * K + k0 + sslot * 8, &As[buf][row * 64 + lslot * 8]);
    }
#pragma unroll
    for (int r = 0; r < 4; r++) {
      int row = r * 32 + lrow8;
      int sslot = lslot ^ (row & 7);
      gload_lds16(Bt + (size_t)(n0 + row) * K + k0 + sslot * 8, &Bs[buf][row * 64 + lslot * 8]);
    }
  };

  f32x4 acc[4][2] = {};
  int nk = K >> 6;
  stage(0, 0);
  __builtin_amdgcn_sched_barrier(0);
  for (int kt = 0; kt < nk; kt++) {
    int cur = kt & 1;
    __builtin_amdgcn_s_barrier();
    __builtin_amdgcn_sched_barrier(0);
    if (kt + 1 < nk) {
      stage(kt + 1, cur ^ 1);
      asm volatile("s_waitcnt vmcnt(6)" ::: "memory");
    } else {
      asm volatile("s_waitcnt vmcnt(0)" ::: "memory");
    }
    __builtin_amdgcn_sched_barrier(0);
    __builtin_amdgcn_s_barrier();
    __builtin_amdgcn_sched_barrier(0);
#pragma unroll
    for (int kk = 0; kk < 2; kk++) {
      bf16x8 af[4], bfr[2];
#pragma unroll
      for (int mi = 0; mi < 4; mi++) {
        int row = mi * 16 + c;
        int sl = (kk * 4 + g) ^ (row & 7);
        af[mi] = *reinterpret_cast<const bf16x8*>(&As[cur][row * 64 + sl * 8]);
      }
#pragma unroll
      for (int ni = 0; ni < 2; ni++) {
        int row = wid * 32 + ni * 16 + c;
        int sl = (kk * 4 + g) ^ (row & 7);
        bfr[ni] = *reinterpret_cast<const bf16x8*>(&Bs[cur][row * 64 + sl * 8]);
      }
#pragma unroll
      for (int mi = 0; mi < 4; mi++)
#pragma unroll
        for (int ni = 0; ni < 2; ni++)
          acc[mi][ni] = __builtin_amdgcn_mfma_f32_16x16x32_bf16(af[mi], bfr[ni], acc[mi][ni], 0, 0, 0);
    }
  }

  if constexpr (EPI == 0) {
#pragma unroll
    for (int mi = 0; mi < 4; mi++)
#pragma unroll
      for (int ni = 0; ni < 2; ni++)
#pragma unroll
        for (int r = 0; r < 4; r++) {
          int row = m0 + mi * 16 + g * 4 + r;
          int col = n0 + wid * 32 + ni * 16 + c;
          C[(size_t)row * N + col] = (OutT)acc[mi][ni][r];
        }
  } else {
    // q-path epilogue: write absorbed Q directly
    bool ropeTile = (n0 >= 256);
#pragma unroll
    for (int mi = 0; mi < 4; mi++)
#pragma unroll
      for (int r = 0; r < 4; r++) {
        int row = m0 + mi * 16 + g * 4 + r;       // token t
        int b = row >> 11, s = row & (S - 1);
#pragma unroll
        for (int ni = 0; ni < 2; ni++) {
          int col = n0 + wid * 32 + ni * 16 + c;
          float val = acc[mi][ni][r];
          if (!ropeTile) {
            int h = col >> 4, cq = col & 15;
            bf16* qrow = Qp + (size_t)((b * 16 + h) * 2048 + s) * 96;
            qrow[64 + cq] = (bf16)(val * KSC);
            qrow[80 + cq] = (bf16)0.f;
          } else {
            int colr = col - 256;
            int h = colr >> 6, jj = colr & 63, j = jj >> 1;
            int pos = pos_ids[row];
            float cf = cos_t[pos * 32 + j], sf = sin_t[pos * 32 + j];
            float other = __shfl_xor(val, 1);
            bf16* qrow = Qp + (size_t)((b * 16 + h) * 2048 + s) * 96;
            if ((c & 1) == 0) {
              qrow[j] = (bf16)((val * cf - other * sf) * KSC);
            } else {
              qrow[32 + j] = (bf16)((val * cf + other * sf) * KSC);
            }
          }
        }
      }
  }
}

// ---------------- absorbed flash attention (round-19 proven layout) ----------------
// 512 blocks: b=lin>>8, u=lin&255; qt = b ? u>>1 : 127-(u>>1) -> each (b,hg,qt) exactly
// once; heavy/light halves anti-correlated; 72KB LDS -> 2 blocks/CU co-resident.
__global__ __launch_bounds__(512, 4) void attn_kernel(
    const bf16* __restrict__ Qp, const bf16* __restrict__ KcG,
    const bf16* __restrict__ cTG, bf16* __restrict__ OC) {
  __shared__ bf16 Kls[128 * 128];     // 32KB
  __shared__ bf16 Cls[2][16 * 128];   // 4KB x2
  __shared__ bf16 Pls[8][16 * 128];   // 4KB per wave

  int lin = blockIdx.x;               // 0..511
  int v = lin >> 8, u = lin & 255;
  int qt = v ? (u >> 1) : (127 - (u >> 1));
  int hg = u & 1, b = v;
  int q0 = qt * 16;
  int nt = qt / 8 + 1;
  int tid = threadIdx.x;
  int w = tid >> 6, lane = tid & 63;
  int g = lane >> 4, cc = lane & 15;
  int h = hg * 8 + w;
  char* pbase = reinterpret_cast<char*>(&Pls[w][0]);

  bf16x8 kst[4];
  auto load_k = [&](int k0) {
#pragma unroll
    for (int i = 0; i < 4; i++) {
      int id = w * 4 + i;
      int key = id * 4 + (lane >> 4);
      int sg = (lane & 15) ^ ((id >> 1) & 15);
      kst[i] = *reinterpret_cast<const bf16x8*>(
          KcG + (((size_t)(b * S + k0 + key)) << 7) + sg * 8);
    }
  };
  auto write_k = [&]() {
#pragma unroll
    for (int i = 0; i < 4; i++) {
      int id = w * 4 + i;
      *reinterpret_cast<bf16x8*>(&Kls[(id * 64 + lane) * 8]) = kst[i];
    }
  };
  auto stage_c = [&](int k0, int buf) {
    if (w >= 4) {
      int c = (w - 4) * 4 + (lane >> 4);
      int sg = (lane & 15) ^ c;
      gload_lds16(cTG + (size_t)(b * 16 + c) * S + k0 + sg * 8,
                  &Cls[buf][(w - 4) * 512]);
    }
  };

  bf16x8 aq[3];
  const bf16* qp = Qp + (size_t)((b * 16 + h) * 2048 + q0 + cc) * 96;
#pragma unroll
  for (int kk = 0; kk < 3; kk++)
    aq[kk] = *reinterpret_cast<const bf16x8*>(qp + kk * 32 + g * 8);

  stage_c(0, 0);
  __builtin_amdgcn_sched_barrier(0);
  load_k(0);
  VMWAIT0;
  write_k();
  if (nt > 1) {
    stage_c(128, 1);
    __builtin_amdgcn_sched_barrier(0);
    load_k(128);
  }
  LGWAIT0;
  __builtin_amdgcn_s_barrier();
  __builtin_amdgcn_sched_barrier(0);

  bf16x8 ones;
#pragma unroll
  for (int j = 0; j < 8; j++) ones[j] = (bf16)1.f;

  f32x4 oc = {}, ls = {};

#pragma unroll 1
  for (int kt = 0; kt < nt; kt++) {
    int cur = kt & 1;
    int k0 = kt * 128;
    f32x4 sacc[8] = {};
    __builtin_amdgcn_s_setprio(1);
#pragma unroll
    for (int kk = 0; kk < 3; kk++)
#pragma unroll
      for (int ntb = 0; ntb < 8; ntb++) {
        int key = cc * 8 + ntb;
        bf16x8 bk = *reinterpret_cast<const bf16x8*>(
            &Kls[(key * 16 + ((kk * 4 + g) ^ cc)) * 8]);
        sacc[ntb] = __builtin_amdgcn_mfma_f32_16x16x32_bf16(aq[kk], bk, sacc[ntb], 0, 0, 0);
      }
    __builtin_amdgcn_s_setprio(0);

    bool diag = (kt == nt - 1);
#pragma unroll
    for (int r = 0; r < 4; r++) {
      bf16x8 pk;
#pragma unroll
      for (int ntb = 0; ntb < 8; ntb++) {
        float x = sacc[ntb][r];
        if (diag) {
          int qr = q0 + g * 4 + r, kc = k0 + cc * 8 + ntb;
          if (kc > qr) x = -1e30f;
        }
        pk[ntb] = (bf16)__builtin_amdgcn_exp2f(x);
      }
      int q = g * 4 + r;
      *reinterpret_cast<bf16x8*>(pbase + (q * 16 + (cc ^ (q & 7))) * 16) = pk;
    }
    LGWAIT0;
    __builtin_amdgcn_s_setprio(1);
#pragma unroll
    for (int kk2 = 0; kk2 < 4; kk2++) {
      bf16x8 pa = *reinterpret_cast<const bf16x8*>(
          pbase + (cc * 16 + ((kk2 * 4 + g) ^ (cc & 7))) * 16);
      bf16x8 bv = *reinterpret_cast<const bf16x8*>(
          &Cls[cur][(cc * 16 + ((kk2 * 4 + g) ^ cc)) * 8]);
      oc = __builtin_amdgcn_mfma_f32_16x16x32_bf16(pa, bv, oc, 0, 0, 0);
      ls = __builtin_amdgcn_mfma_f32_16x16x32_bf16(pa, ones, ls, 0, 0, 0);
    }
    __builtin_amdgcn_s_setprio(0);

    if (kt + 1 < nt) {
      __builtin_amdgcn_s_barrier();
      __builtin_amdgcn_sched_barrier(0);
      VMWAIT0;
      write_k();
      if (kt + 2 < nt) {
        stage_c((kt + 2) * 128, cur);
        __builtin_amdgcn_sched_barrier(0);
        load_k((kt + 2) * 128);
      }
      LGWAIT0;
      __builtin_amdgcn_s_barrier();
      __builtin_amdgcn_sched_barrier(0);
    }
  }

#pragma unroll
  for (int r = 0; r < 4; r++) {
    size_t t = (size_t)b * S + q0 + g * 4 + r;
    OC[t * 256 + h * 16 + cc] = (bf16)(oc[r] / ls[r]);
  }
}

// ---------------- host ----------------
extern "C" void kernel_launch(void* const* d_in, const int* in_sizes, int n_in,
                              void* d_out, int out_size, void* d_ws, size_t ws_size,
                              hipStream_t stream) {
  const float* inputs    = (const float*)d_in[0];
  const int*   pos_ids   = (const int*)d_in[1];
  const float* Wq_down   = (const float*)d_in[3];
  const float* q_norm_w  = (const float*)d_in[4];
  const float* Wq_up     = (const float*)d_in[5];
  const float* Wkv_down  = (const float*)d_in[6];
  const float* kv_norm_w = (const float*)d_in[7];
  const float* Wkv_up    = (const float*)d_in[8];
  const float* Wout      = (const float*)d_in[9];
  float* out = (float*)d_out;

  char* ws = (char*)d_ws;
  size_t off = 0;
  auto alloc = [&](size_t bytes) -> void* {
    void* p = ws + off;
    off += (bytes + 255) & ~(size_t)255;
    return p;
  };

  bf16*  in_bf = (bf16*)alloc((size_t)T * D * 2);
  bf16*  WdT   = (bf16*)alloc((size_t)NDNP * D * 2);
  bf16*  WqxT  = (bf16*)alloc((size_t)NQX * DC_Q * 2);
  bf16*  W2T   = (bf16*)alloc((size_t)D * 256 * 2);
  bf16*  cqkv  = (bf16*)alloc((size_t)T * NDNP * 2);
  bf16*  cqn   = (bf16*)alloc((size_t)T * DC_Q * 2);
  bf16*  KcG   = (bf16*)alloc((size_t)T * 128 * 2);
  bf16*  cTG   = (bf16*)alloc((size_t)B * 16 * S * 2);
  bf16*  Qp    = (bf16*)alloc((size_t)B * H * S * 96 * 2);
  bf16*  OC    = (bf16*)alloc((size_t)T * H * 16 * 2);
  float* cos_t = (float*)alloc((size_t)S * 32 * 4);
  float* sin_t = (float*)alloc((size_t)S * 32 * 4);

  prologue_kernel<<<2832, 256, 0, stream>>>(
      inputs, Wq_down, Wq_up, Wkv_down, Wkv_up, Wout,
      in_bf, WdT, WqxT, W2T, cos_t, sin_t);

  gemm_bt_kernel<bf16, 0><<<dim3(NDNP / 128, T / 64), 256, 0, stream>>>(
      in_bf, WdT, cqkv, T, NDNP, D);
  norm_kv_kernel<<<T / 4, 256, 0, stream>>>(
      cqkv, q_norm_w, kv_norm_w, pos_ids, cos_t, sin_t, cqn, KcG, cTG);
  gemm_bt_kernel<bf16, 1><<<dim3(NQX / 128, T / 64), 256, 0, stream>>>(
      cqn, WqxT, (bf16*)nullptr, T, NQX, DC_Q, pos_ids, cos_t, sin_t, Qp);
  attn_kernel<<<512, 512, 0, stream>>>(Qp, KcG, cTG, OC);
  gemm_bt_kernel<float, 0><<<dim3(D / 128, T / 64), 256, 0, stream>>>(
      OC, W2T, out, T, D, 256);
}